// Round 2
// baseline (41340.244 us; speedup 1.0000x reference)
//
#include <hip/hip_runtime.h>
#include <stdint.h>

// DSNN bit-exact fp32. Locked-in facts:
//  - Ref is k-ascending single-accumulator fma (R1/R4/R5/R6 absmax 0.0); any
//    reorder/reprecision flips spikes chaotically (R2: 511). Dense fmaf with
//    spike in {0.0,1.0} is bitwise == conditional add. No MFMA (no fp32 MFMA).
//  - Pipe model per CU-j (16 waves, 1 block/CU): VALU(fma)=128 cyc, TCP
//    (W dwordx2) = 128 cyc, LDS b128 broadcast ~9.5 cyc each.
//    R7 (f32 spikes, 2 bcast/wave-j): LDS 304 -> 33.0 ms, LDS-bound.
//    R8 (f16 spikes + v_fma_mix): 39.8 ms, VALUBusy 74% -> mix is HALF-RATE
//    on gfx950 (4cyc/wave64): VALU 256 cyc. Inline asm also dropped VGPR to 64.
//  - R9 (this): spikes packed as UPPER-HALF-OF-F32 (1.0f -> 0x3F80 in a u16):
//    8 rows in ONE b128 broadcast; expansion is 1 full-rate bit op per row
//    (d<<16 / d&0xFFFF0000), exact {0f,1f}. Per wave-j: 1 LDS + 24 VALU.
//    Model: VALU 192 (bound) > LDS 152 > TCP 128 -> ~21 ms predicted.

typedef __attribute__((ext_vector_type(2))) float f32x2;
typedef __attribute__((ext_vector_type(4))) float f32x4;

#define ALPHA 0.9f
#define BETA 0.85f
#define NSTEPS 127
#define WGT 1024
#define ROWS 32
#define CPAD 36     // x-stage f32 col stride (floats): 32 rows + 4 pad
#define SPH 20      // packed-spike col stride (dwords): 16 dw (32 rows) + 4 pad = 80 B (16B mult)
#define HPAD 516    // h0buf row stride (floats)

// Update forms verbatim from R1/R4 (bit-exact-verified vs np reference),
// spike output as bool for packing.
#define LIF_L0(M, H, B) { float _m = BETA * (M) + (H); \
    (B) = (_m - 1.0f) > 0.0f; (M) = (B) ? 0.0f : _m; }
#define LIF_MID(S, M, A, B) { (S) = ALPHA * (S) + (A); \
    float _m = BETA * (M) + (S); (B) = (_m - 1.0f) > 0.0f; \
    (M) = (B) ? 0.0f : _m; }
#define LIF_OUT(S, M, A) { (S) = ALPHA * (S) + (A); (M) = BETA * (M) + (S); }

// Pack two row-spikes into one dword as upper-half-of-f32 encodings:
// lo u16 (even row): 0x3F80 -> (d<<16) == 0x3F800000 == 1.0f
// hi u16 (odd  row): 0x3F80 in bits 31:16 -> (d & 0xFFFF0000) == 1.0f
#define PACK2(L, H) (((L) ? 0x3F80u : 0u) | ((H) ? 0x3F800000u : 0u))

__global__ __launch_bounds__(WGT, 4)
void dsnn_kernel(const float* __restrict__ x,
                 const float* __restrict__ W0,
                 const float* __restrict__ W1,
                 const float* __restrict__ W2,
                 float* __restrict__ out)
{
    __shared__ float spkbuf[512 * CPAD];   // 73728 B; x-stage f32, then packed spikes
    __shared__ float h0buf[ROWS * HPAD];   // 66048 B, [row][col]
    uint32_t* spkh = (uint32_t*)spkbuf;    // packed-spike view: [col][dword], stride SPH

    const int t  = threadIdx.x;
    const int c2 = (t & 255) * 2;          // cols c2, c2+1
    const int g  = (t >> 8) * 8;           // rows g..g+7 (wave-uniform)
    const int gd = g >> 1;                 // dword offset of row-group in a packed col
    const int r0 = blockIdx.x * ROWS;

    // ---- stage x (pos/neg split) into spkbuf [i][row], i = 0..255 ----
    for (int k = t; k < 256 * ROWS; k += WGT) {
        const int i = k >> 5;
        const int r = k & 31;
        const float v = (i < 128) ? x[(size_t)(r0 + r) * 128 + i]
                                  : -x[(size_t)(r0 + r) * 128 + (i - 128)];
        spkbuf[i * CPAD + r] = fmaxf(v, 0.0f);
    }
    __syncthreads();

    float acc[8][2];   // [row r][col cc]

    // f32 gemm over real-valued x (h0 phase only); j ascending (bit-exact order)
    auto gemm_x = [&](const float* Wcol, int K) {
        #pragma unroll 2
        for (int j = 0; j < K; ++j) {
            const float* sb = spkbuf + j * CPAD + g;       // wave-uniform -> broadcast
            const f32x4 sA = *(const f32x4*)(sb);          // rows g..g+3
            const f32x4 sB = *(const f32x4*)(sb + 4);      // rows g+4..g+7
            const f32x2 wv = *(const f32x2*)(Wcol + (size_t)j * 512);
            #pragma unroll
            for (int rr = 0; rr < 4; ++rr) {
                acc[rr][0]     = fmaf(sA[rr], wv.x, acc[rr][0]);
                acc[rr][1]     = fmaf(sA[rr], wv.y, acc[rr][1]);
                acc[4 + rr][0] = fmaf(sB[rr], wv.x, acc[4 + rr][0]);
                acc[4 + rr][1] = fmaf(sB[rr], wv.y, acc[4 + rr][1]);
            }
        }
    };

    // Packed-spike gemm: ONE broadcast b128 per wave-j delivers 8 rows.
    // dword k of a col = rows 2k (lo u16), 2k+1 (hi u16); matches pack order.
    // Expansion is one full-rate bit op per row, yielding exactly 0.0f / 1.0f.
    auto gemm_h = [&](const float* Wcol, int K) {
        #pragma unroll 2
        for (int j = 0; j < K; ++j) {
            const uint4 sp = *(const uint4*)(spkh + j * SPH + gd);
            const f32x2 wv = *(const f32x2*)(Wcol + (size_t)j * 512);
            float s[8];
            s[0] = __uint_as_float(sp.x << 16);
            s[1] = __uint_as_float(sp.x & 0xFFFF0000u);
            s[2] = __uint_as_float(sp.y << 16);
            s[3] = __uint_as_float(sp.y & 0xFFFF0000u);
            s[4] = __uint_as_float(sp.z << 16);
            s[5] = __uint_as_float(sp.z & 0xFFFF0000u);
            s[6] = __uint_as_float(sp.w << 16);
            s[7] = __uint_as_float(sp.w & 0xFFFF0000u);
            #pragma unroll
            for (int r = 0; r < 8; ++r) {
                acc[r][0] = fmaf(s[r], wv.x, acc[r][0]);
                acc[r][1] = fmaf(s[r], wv.y, acc[r][1]);
            }
        }
    };

    // ---- h0 = x @ W0 (time-invariant), park in LDS ----
    #pragma unroll
    for (int r = 0; r < 8; ++r) { acc[r][0] = 0.0f; acc[r][1] = 0.0f; }
    gemm_x(W0 + c2, 256);
    #pragma unroll
    for (int r = 0; r < 8; ++r) {
        f32x2 hv = { acc[r][0], acc[r][1] };
        *(f32x2*)(h0buf + (g + r) * HPAD + c2) = hv;
    }
    __syncthreads();   // all x-reads done before spkbuf is reused for packed spikes

    // ---- recurrent state in registers: 5 x 16 = 80 ----
    float m0[8][2], s1[8][2], m1[8][2], s2[8][2], m2[8][2];
    #pragma unroll
    for (int r = 0; r < 8; ++r)
        #pragma unroll
        for (int cc = 0; cc < 2; ++cc) {
            m0[r][cc] = 0.f; s1[r][cc] = 0.f; m1[r][cc] = 0.f;
            s2[r][cc] = 0.f; m2[r][cc] = 0.f;
        }

    for (int step = 0; step < NSTEPS; ++step) {
        // ===== layer 0: m0 = BETA*m0 + h0; spike; reset; packed spikes -> LDS =====
        {
            bool bA[2][4], bB[2][4];   // [cc][rr]: rows g+rr / g+4+rr
            #pragma unroll
            for (int rr = 0; rr < 4; ++rr) {
                const f32x2 hva = *(const f32x2*)(h0buf + (g + rr) * HPAD + c2);
                const f32x2 hvb = *(const f32x2*)(h0buf + (g + 4 + rr) * HPAD + c2);
                LIF_L0(m0[rr][0], hva.x, bA[0][rr]);
                LIF_L0(m0[rr][1], hva.y, bA[1][rr]);
                LIF_L0(m0[4 + rr][0], hvb.x, bB[0][rr]);
                LIF_L0(m0[4 + rr][1], hvb.y, bB[1][rr]);
            }
            #pragma unroll
            for (int cc = 0; cc < 2; ++cc) {
                uint4 pk;
                pk.x = PACK2(bA[cc][0], bA[cc][1]);   // rows g+0, g+1
                pk.y = PACK2(bA[cc][2], bA[cc][3]);   // rows g+2, g+3
                pk.z = PACK2(bB[cc][0], bB[cc][1]);   // rows g+4, g+5
                pk.w = PACK2(bB[cc][2], bB[cc][3]);   // rows g+6, g+7
                *(uint4*)(spkh + (c2 + cc) * SPH + gd) = pk;
            }
        }
        __syncthreads();                       // A: L0 spikes visible

        // ===== layer 1: h1 = spk0 @ W1 =====
        #pragma unroll
        for (int r = 0; r < 8; ++r) { acc[r][0] = 0.0f; acc[r][1] = 0.0f; }
        gemm_h(W1 + c2, 512);
        __syncthreads();                       // B: all reads of L0 spikes done

        {
            bool bA[2][4], bB[2][4];
            #pragma unroll
            for (int rr = 0; rr < 4; ++rr) {
                LIF_MID(s1[rr][0], m1[rr][0], acc[rr][0], bA[0][rr]);
                LIF_MID(s1[rr][1], m1[rr][1], acc[rr][1], bA[1][rr]);
                LIF_MID(s1[4 + rr][0], m1[4 + rr][0], acc[4 + rr][0], bB[0][rr]);
                LIF_MID(s1[4 + rr][1], m1[4 + rr][1], acc[4 + rr][1], bB[1][rr]);
            }
            #pragma unroll
            for (int cc = 0; cc < 2; ++cc) {
                uint4 pk;
                pk.x = PACK2(bA[cc][0], bA[cc][1]);
                pk.y = PACK2(bA[cc][2], bA[cc][3]);
                pk.z = PACK2(bB[cc][0], bB[cc][1]);
                pk.w = PACK2(bB[cc][2], bB[cc][3]);
                *(uint4*)(spkh + (c2 + cc) * SPH + gd) = pk;
            }
        }
        __syncthreads();                       // C: L1 spikes visible

        // ===== layer 2: h2 = spk1 @ W2; s2,m2 update; no reset =====
        #pragma unroll
        for (int r = 0; r < 8; ++r) { acc[r][0] = 0.0f; acc[r][1] = 0.0f; }
        gemm_h(W2 + c2, 512);
        #pragma unroll
        for (int r = 0; r < 8; ++r) {
            LIF_OUT(s2[r][0], m2[r][0], acc[r][0]);
            LIF_OUT(s2[r][1], m2[r][1], acc[r][1]);
        }
        __syncthreads();                       // D: L1-spike reads done before next L0 write
    }

    // ---- write final m2 ----
    #pragma unroll
    for (int r = 0; r < 8; ++r) {
        f32x2 ov = { m2[r][0], m2[r][1] };
        *(f32x2*)(out + (size_t)(r0 + g + r) * 512 + c2) = ov;
    }
}

extern "C" void kernel_launch(void* const* d_in, const int* in_sizes, int n_in,
                              void* d_out, int out_size, void* d_ws, size_t ws_size,
                              hipStream_t stream) {
    const float* inputs = (const float*)d_in[0];   // 16384 x 128
    const float* W0     = (const float*)d_in[1];   // 256 x 512
    const float* W1     = (const float*)d_in[2];   // 512 x 512
    const float* W2     = (const float*)d_in[3];   // 512 x 512
    float* out          = (float*)d_out;           // 16384 x 512

    dim3 grid(16384 / ROWS);     // 512 workgroups, 32 rows each
    dim3 block(WGT);
    dsnn_kernel<<<grid, block, 0, stream>>>(inputs, W0, W1, W2, out);
}

// Round 4
// 33025.876 us; speedup vs baseline: 1.2518x; 1.2518x over previous
//
#include <hip/hip_runtime.h>
#include <stdint.h>

// DSNN bit-exact fp32. Locked-in facts:
//  - Ref is k-ascending single-accumulator fma (R1/R4/R5/R6 absmax 0.0); any
//    reorder/reprecision flips spikes chaotically (R2: 511). Dense fma with
//    spike in {0.0,1.0} is bitwise == conditional add. No MFMA (no fp32 MFMA).
//  - ISSUE-BOUND (R7/R8/R9 fit): T/SIMD-j ~= 7.0*inst + 0.67*valu_pipe + 55.
//    R7 (f32 spikes, 21 inst, pipe 152) = 304 cyc -> 33.0 ms.
//    R8 (f16 + v_fma_mix HALF-RATE, 20 inst, pipe 256) = 367 -> 39.8 ms.
//    R9 (u16-pack + 8 bit-expand, 28 inst, pipe 192) = 381 -> 41.3 ms.
//    VALUBusy*dur/inst ~= 3.0 cyc/inst in all rounds: per-instruction issue
//    is the cost; LDS broadcasts are NOT the bound (halving them didn't help).
//  - R10/R11 (this; R10 bench was an infra failure, resubmitted unchanged):
//    v_pk_fma_f32 = 2 IEEE f32 fma / 1 instruction. Col pair
//    (acc[r][0],acc[r][1]) x (wv.x,wv.y) is exactly the packed shape; row
//    spike broadcast to both halves via op_sel/op_sel_hi (no dup movs).
//    f32 spikes in LDS (no expansion ops). 13 inst/wave-j -> ~242 cyc
//    -> predict ~26 ms. Bit-exact: each half is a standard f32 fma.

typedef __attribute__((ext_vector_type(2))) float f32x2;
typedef __attribute__((ext_vector_type(4))) float f32x4;

#define ALPHA 0.9f
#define BETA 0.85f
#define NSTEPS 127
#define WGT 1024
#define ROWS 32
#define CPAD 36     // spkbuf col stride (floats): 32 rows + 4 pad
#define HPAD 516    // h0buf row stride (floats)

// Update forms verbatim from R1/R4 (bit-exact-verified vs np reference).
#define LIF_L0(M, H, SP) { float _m = BETA * (M) + (H); \
    const bool _b = (_m - 1.0f) > 0.0f; (M) = _b ? 0.0f : _m; \
    (SP) = _b ? 1.0f : 0.0f; }
#define LIF_MID(S, M, A, SP) { (S) = ALPHA * (S) + (A); \
    float _m = BETA * (M) + (S); const bool _b = (_m - 1.0f) > 0.0f; \
    (M) = _b ? 0.0f : _m; (SP) = _b ? 1.0f : 0.0f; }
#define LIF_OUT(S, M, A) { (S) = ALPHA * (S) + (A); (M) = BETA * (M) + (S); }

__global__ __launch_bounds__(WGT, 4)
void dsnn_kernel(const float* __restrict__ x,
                 const float* __restrict__ W0,
                 const float* __restrict__ W1,
                 const float* __restrict__ W2,
                 float* __restrict__ out)
{
    __shared__ float spkbuf[512 * CPAD];   // 73728 B, [index][row] (x-stage, then spikes)
    __shared__ float h0buf[ROWS * HPAD];   // 66048 B, [row][col]

    const int t  = threadIdx.x;
    const int c2 = (t & 255) * 2;          // cols c2, c2+1
    const int g  = (t >> 8) * 8;           // rows g..g+7 (wave-uniform)
    const int r0 = blockIdx.x * ROWS;

    // ---- stage x (pos/neg split) into spkbuf [i][row], i = 0..255 ----
    for (int k = t; k < 256 * ROWS; k += WGT) {
        const int i = k >> 5;
        const int r = k & 31;
        const float v = (i < 128) ? x[(size_t)(r0 + r) * 128 + i]
                                  : -x[(size_t)(r0 + r) * 128 + (i - 128)];
        spkbuf[i * CPAD + r] = fmaxf(v, 0.0f);
    }
    __syncthreads();

    f32x2 acc2[8];   // [row r] = (col c2, col c2+1)

    // acc2[r] += buf[j][g+r] * (W[j][c2], W[j][c2+1]), j ascending (bit-exact
    // order, each half an independent IEEE f32 fma chain).
    // v_pk_fma_f32: 2 fma / instruction; row spike broadcast to both halves:
    //   lo-bcast: op_sel:[0,0,0] op_sel_hi:[0,1,1]  (both halves read src0.lo)
    //   hi-bcast: op_sel:[1,0,0] op_sel_hi:[1,1,1]  (both halves read src0.hi)
    auto gemm = [&](const float* Wcol, int K) {
        #pragma unroll 2
        for (int j = 0; j < K; ++j) {
            const float* sb = spkbuf + j * CPAD + g;       // wave-uniform -> broadcast
            const f32x4 sA = *(const f32x4*)(sb);          // rows g..g+3
            const f32x4 sB = *(const f32x4*)(sb + 4);      // rows g+4..g+7
            const f32x2 wv = *(const f32x2*)(Wcol + (size_t)j * 512);
            f32x2 a01 = { sA[0], sA[1] };   // sub-pairs of the b128 quads (free)
            f32x2 a23 = { sA[2], sA[3] };
            f32x2 b01 = { sB[0], sB[1] };
            f32x2 b23 = { sB[2], sB[3] };
            asm("v_pk_fma_f32 %0, %8, %12, %0 op_sel:[0,0,0] op_sel_hi:[0,1,1]\n\t"
                "v_pk_fma_f32 %1, %8, %12, %1 op_sel:[1,0,0] op_sel_hi:[1,1,1]\n\t"
                "v_pk_fma_f32 %2, %9, %12, %2 op_sel:[0,0,0] op_sel_hi:[0,1,1]\n\t"
                "v_pk_fma_f32 %3, %9, %12, %3 op_sel:[1,0,0] op_sel_hi:[1,1,1]\n\t"
                "v_pk_fma_f32 %4, %10, %12, %4 op_sel:[0,0,0] op_sel_hi:[0,1,1]\n\t"
                "v_pk_fma_f32 %5, %10, %12, %5 op_sel:[1,0,0] op_sel_hi:[1,1,1]\n\t"
                "v_pk_fma_f32 %6, %11, %12, %6 op_sel:[0,0,0] op_sel_hi:[0,1,1]\n\t"
                "v_pk_fma_f32 %7, %11, %12, %7 op_sel:[1,0,0] op_sel_hi:[1,1,1]"
                : "+v"(acc2[0]), "+v"(acc2[1]), "+v"(acc2[2]), "+v"(acc2[3]),
                  "+v"(acc2[4]), "+v"(acc2[5]), "+v"(acc2[6]), "+v"(acc2[7])
                : "v"(a01), "v"(a23), "v"(b01), "v"(b23), "v"(wv));
        }
    };

    // ---- h0 = x @ W0 (time-invariant), park in LDS ----
    #pragma unroll
    for (int r = 0; r < 8; ++r) acc2[r] = (f32x2){ 0.0f, 0.0f };
    gemm(W0 + c2, 256);
    #pragma unroll
    for (int r = 0; r < 8; ++r)
        *(f32x2*)(h0buf + (g + r) * HPAD + c2) = acc2[r];
    __syncthreads();   // all x-reads done before spkbuf is reused for spikes

    // ---- recurrent state in registers: 5 x 16 = 80 ----
    float m0[8][2], s1[8][2], m1[8][2], s2[8][2], m2[8][2];
    #pragma unroll
    for (int r = 0; r < 8; ++r)
        #pragma unroll
        for (int cc = 0; cc < 2; ++cc) {
            m0[r][cc] = 0.f; s1[r][cc] = 0.f; m1[r][cc] = 0.f;
            s2[r][cc] = 0.f; m2[r][cc] = 0.f;
        }

    for (int step = 0; step < NSTEPS; ++step) {
        // ===== layer 0: m0 = BETA*m0 + h0; spike; reset; spikes -> spkbuf =====
        {
            f32x4 svA[2], svB[2];   // [cc] rows g..g+3 / g+4..g+7
            #pragma unroll
            for (int rr = 0; rr < 4; ++rr) {
                const f32x2 hva = *(const f32x2*)(h0buf + (g + rr) * HPAD + c2);
                const f32x2 hvb = *(const f32x2*)(h0buf + (g + 4 + rr) * HPAD + c2);
                LIF_L0(m0[rr][0], hva.x, svA[0][rr]);
                LIF_L0(m0[rr][1], hva.y, svA[1][rr]);
                LIF_L0(m0[4 + rr][0], hvb.x, svB[0][rr]);
                LIF_L0(m0[4 + rr][1], hvb.y, svB[1][rr]);
            }
            #pragma unroll
            for (int cc = 0; cc < 2; ++cc) {
                *(f32x4*)(spkbuf + (c2 + cc) * CPAD + g)     = svA[cc];
                *(f32x4*)(spkbuf + (c2 + cc) * CPAD + g + 4) = svB[cc];
            }
        }
        __syncthreads();                       // A: L0 spikes visible

        // ===== layer 1: h1 = spk0 @ W1 =====
        #pragma unroll
        for (int r = 0; r < 8; ++r) acc2[r] = (f32x2){ 0.0f, 0.0f };
        gemm(W1 + c2, 512);
        __syncthreads();                       // B: all reads of L0 spikes done

        {
            f32x4 svA[2], svB[2];
            #pragma unroll
            for (int rr = 0; rr < 4; ++rr) {
                LIF_MID(s1[rr][0], m1[rr][0], acc2[rr][0], svA[0][rr]);
                LIF_MID(s1[rr][1], m1[rr][1], acc2[rr][1], svA[1][rr]);
                LIF_MID(s1[4 + rr][0], m1[4 + rr][0], acc2[4 + rr][0], svB[0][rr]);
                LIF_MID(s1[4 + rr][1], m1[4 + rr][1], acc2[4 + rr][1], svB[1][rr]);
            }
            #pragma unroll
            for (int cc = 0; cc < 2; ++cc) {
                *(f32x4*)(spkbuf + (c2 + cc) * CPAD + g)     = svA[cc];
                *(f32x4*)(spkbuf + (c2 + cc) * CPAD + g + 4) = svB[cc];
            }
        }
        __syncthreads();                       // C: L1 spikes visible

        // ===== layer 2: h2 = spk1 @ W2; s2,m2 update; no reset =====
        #pragma unroll
        for (int r = 0; r < 8; ++r) acc2[r] = (f32x2){ 0.0f, 0.0f };
        gemm(W2 + c2, 512);
        #pragma unroll
        for (int r = 0; r < 8; ++r) {
            LIF_OUT(s2[r][0], m2[r][0], acc2[r][0]);
            LIF_OUT(s2[r][1], m2[r][1], acc2[r][1]);
        }
        __syncthreads();                       // D: L1-spike reads done before next L0 write
    }

    // ---- write final m2 ----
    #pragma unroll
    for (int r = 0; r < 8; ++r) {
        f32x2 ov = { m2[r][0], m2[r][1] };
        *(f32x2*)(out + (size_t)(r0 + g + r) * 512 + c2) = ov;
    }
}

extern "C" void kernel_launch(void* const* d_in, const int* in_sizes, int n_in,
                              void* d_out, int out_size, void* d_ws, size_t ws_size,
                              hipStream_t stream) {
    const float* inputs = (const float*)d_in[0];   // 16384 x 128
    const float* W0     = (const float*)d_in[1];   // 256 x 512
    const float* W1     = (const float*)d_in[2];   // 512 x 512
    const float* W2     = (const float*)d_in[3];   // 512 x 512
    float* out          = (float*)d_out;           // 16384 x 512

    dim3 grid(16384 / ROWS);     // 512 workgroups, 32 rows each
    dim3 block(WGT);
    dsnn_kernel<<<grid, block, 0, stream>>>(inputs, W0, W1, W2, out);
}